// Round 7
// baseline (5628.288 us; speedup 1.0000x reference)
//
#include <hip/hip_runtime.h>

#define T_STEPS 512
#define HS 20       // hidden size
#define F0 10       // input features (layer 0)
#define NB_TOT 4096
#define NBLK (NB_TOT / 2)     // 2048 blocks, 2 batches per block -> EXACT, no tails
#define CHK 32                // chunk length (steps per barrier region)
#define NCH (T_STEPS / CHK)   // 16 chunks

__device__ __forceinline__ float sigmoid_fast(float v) {
    return __fdividef(1.f, 1.f + __expf(-v));
}
__device__ __forceinline__ float tanh_fast(float v) {
    return 1.f - __fdividef(2.f, __expf(2.f * v) + 1.f);
}
#define PIN(v) asm volatile("" : "+v"(v))

__device__ __forceinline__ float rdlane(float v, int l) {
    return __uint_as_float(__builtin_amdgcn_readlane(__float_as_uint(v), l));
}

// Barrier-free recurrence: one wave = one LAYER for 2 batches, self-contained.
//   lanes  0-19 (role 0): gate rows {i,f} for unit ul, both batches + c/h finish
//   lanes 20-39 (role 1): gate rows {g,o} for unit ul, both batches
//   lanes 40-63: benign duplicates of role 0 rows (results never read)
// Per-step exchanges are INTRA-WAVE: (tanh g, sig o) -> finisher via 4 __shfl;
// h(t) -> all lanes via 40 v_readlane into SGPRs (FMA scalar operand). No LDS,
// no __syncthreads in the recurrence. L0->L1 handoff: R1-style 32-step chunk
// double buffer (17 barriers total). x staged per chunk through LDS with an
// exact 640 = 64 lanes x 10 element map (no clamps; div/mod off the hot path).
// Accumulation orders operand-identical to verified R2/R6 (bias -> x asc ->
// h asc ; bias -> h0 asc -> h1 asc ; c = sig(f)*c + sig(i)*tanh(g)).
// Grid: 2048 blocks x 128 thr at (128,4) -> 4096 waves = ONE residency round.
__global__ __launch_bounds__(128, 4)
void lstm2_fc_kernel(const float* __restrict__ x,
                     const float* __restrict__ wih0, const float* __restrict__ whh0,
                     const float* __restrict__ bih0, const float* __restrict__ bhh0,
                     const float* __restrict__ wih1, const float* __restrict__ whh1,
                     const float* __restrict__ bih1, const float* __restrict__ bhh1,
                     const float* __restrict__ wfc,  const float* __restrict__ bfc,
                     float* __restrict__ out)
{
    const int tid  = threadIdx.x;
    const int wid  = tid >> 6;          // 0: layer0 wave, 1: layer1 wave
    const int lane = tid & 63;
    const int ul   = lane % HS;
    const int role = lane / HS;         // 0,1,2 (+ lanes 60-63 -> 3)
    const int q0   = (role == 1) ? 2 : 0;   // roles 2,3 duplicate role-0 rows
    const int b0   = blockIdx.x * 2;
    const int b1   = b0 + 1;

    __shared__ float hbuf[2][CHK][2][HS];   // h0 chunk double buffer
    __shared__ float xbuf[2][CHK][2][F0];   // x  chunk double buffer

    // ---- per-lane weights: 2 gate rows for my layer ----
    // L0: w0/w1[0..9] = wih0 row, [10..29] = whh0 row
    // L1: w0/w1[0..19] = wih1 row, [20..39] = whh1 row
    float w0[2 * HS], w1[2 * HS], bias0, bias1;
    {
        const int r0 = q0 * HS + ul, r1 = (q0 + 1) * HS + ul;
        if (wid == 0) {
            #pragma unroll
            for (int f = 0; f < F0; ++f) {
                w0[f] = wih0[r0 * F0 + f]; PIN(w0[f]);
                w1[f] = wih0[r1 * F0 + f]; PIN(w1[f]);
            }
            #pragma unroll
            for (int j = 0; j < HS; ++j) {
                w0[F0 + j] = whh0[r0 * HS + j]; PIN(w0[F0 + j]);
                w1[F0 + j] = whh0[r1 * HS + j]; PIN(w1[F0 + j]);
            }
            bias0 = bih0[r0] + bhh0[r0]; PIN(bias0);
            bias1 = bih0[r1] + bhh0[r1]; PIN(bias1);
        } else {
            #pragma unroll
            for (int j = 0; j < HS; ++j) {
                w0[j] = wih1[r0 * HS + j]; PIN(w0[j]);
                w1[j] = wih1[r1 * HS + j]; PIN(w1[j]);
            }
            #pragma unroll
            for (int j = 0; j < HS; ++j) {
                w0[HS + j] = whh1[r0 * HS + j]; PIN(w0[HS + j]);
                w1[HS + j] = whh1[r1 * HS + j]; PIN(w1[HS + j]);
            }
            bias0 = bih1[r0] + bhh1[r0]; PIN(bias0);
            bias1 = bih1[r1] + bhh1[r1]; PIN(bias1);
        }
    }

    float cA = 0.f, cB = 0.f;           // cell state (meaningful in role-0 lanes)
    float hsA[HS], hsB[HS];             // uniform (SGPR) h(t-1) of MY layer
    #pragma unroll
    for (int j = 0; j < HS; ++j) { hsA[j] = 0.f; hsB[j] = 0.f; }

    // ---- prologue: wave0 stages x chunk 0 ----
    // element e = lane + 64*r : s = e/20, b = (e%20)/10, f = e%10 (640 exact)
    if (wid == 0) {
        float xst[10];
        #pragma unroll
        for (int r = 0; r < 10; ++r) {
            const int e = lane + 64 * r;
            const int s = e / HS, rem = e % HS;
            const int b = rem / F0, f = rem % F0;
            xst[r] = x[(size_t)(b0 + b) * (T_STEPS * F0) + s * F0 + f];
        }
        #pragma unroll
        for (int r = 0; r < 10; ++r)
            (&xbuf[0][0][0][0])[lane + 64 * r] = xst[r];
    }
    __syncthreads();

    for (int k = 0; k <= NCH; ++k) {
        if (wid == 0) {
            if (k < NCH) {
                // issue next x chunk loads (consumed by ds_write at region end)
                const bool st = (k + 1 < NCH);
                float xst[10];
                if (st) {
                    #pragma unroll
                    for (int r = 0; r < 10; ++r) {
                        const int e = lane + 64 * r;
                        const int s = e / HS, rem = e % HS;
                        const int b = rem / F0, f = rem % F0;
                        xst[r] = x[(size_t)(b0 + b) * (T_STEPS * F0)
                                   + ((k + 1) * CHK + s) * F0 + f];
                    }
                }
                const float* xr = &xbuf[k & 1][0][0][0];
                float* hw = &hbuf[k & 1][0][0][0];
                #pragma unroll 1
                for (int s = 0; s < CHK; ++s) {
                    float a0A = bias0, a1A = bias1, a0B = bias0, a1B = bias1;
                    // x part, ascending f (float2 granularity as in R2/R6)
                    const float2* xpA = (const float2*)(xr + s * (2 * F0));
                    const float2* xpB = (const float2*)(xr + s * (2 * F0) + F0);
                    #pragma unroll
                    for (int f2 = 0; f2 < F0 / 2; ++f2) {
                        const float2 vA = xpA[f2], vB = xpB[f2];
                        a0A = fmaf(vA.x, w0[2*f2], a0A); a0A = fmaf(vA.y, w0[2*f2+1], a0A);
                        a1A = fmaf(vA.x, w1[2*f2], a1A); a1A = fmaf(vA.y, w1[2*f2+1], a1A);
                        a0B = fmaf(vB.x, w0[2*f2], a0B); a0B = fmaf(vB.y, w0[2*f2+1], a0B);
                        a1B = fmaf(vB.x, w1[2*f2], a1B); a1B = fmaf(vB.y, w1[2*f2+1], a1B);
                    }
                    // h0(t-1) part, ascending j, from SGPR broadcast
                    #pragma unroll
                    for (int j = 0; j < HS; ++j) {
                        a0A = fmaf(hsA[j], w0[F0 + j], a0A);
                        a1A = fmaf(hsA[j], w1[F0 + j], a1A);
                        a0B = fmaf(hsB[j], w0[F0 + j], a0B);
                        a1B = fmaf(hsB[j], w1[F0 + j], a1B);
                    }
                    // activations: role0 -> sig(i),sig(f); role1 -> tanh(g),sig(o)
                    const float act0A = (role == 1) ? tanh_fast(a0A) : sigmoid_fast(a0A);
                    const float act1A = sigmoid_fast(a1A);
                    const float act0B = (role == 1) ? tanh_fast(a0B) : sigmoid_fast(a0B);
                    const float act1B = sigmoid_fast(a1B);
                    // (tanh g, sig o) -> role-0 lanes via intra-wave shfl
                    const int sl = HS + ul;
                    const float tgA = __shfl(act0A, sl), soA = __shfl(act1A, sl);
                    const float tgB = __shfl(act0B, sl), soB = __shfl(act1B, sl);
                    // finish (all lanes execute; only role-0 values are read)
                    cA = fmaf(act1A, cA, act0A * tgA);   // c = sig(f)*c + sig(i)*tanh(g)
                    cB = fmaf(act1B, cB, act0B * tgB);
                    const float hA = soA * tanh_fast(cA);
                    const float hB = soB * tanh_fast(cB);
                    if (role == 0) {
                        hw[s * (2 * HS) + ul]      = hA;   // hbuf[k&1][s][0][ul]
                        hw[s * (2 * HS) + HS + ul] = hB;   // hbuf[k&1][s][1][ul]
                    }
                    // broadcast h(t) to all lanes (SGPRs) for next step
                    #pragma unroll
                    for (int j = 0; j < HS; ++j) {
                        hsA[j] = rdlane(hA, j);
                        hsB[j] = rdlane(hB, j);
                    }
                }
                if (st) {
                    float* xw = &xbuf[(k + 1) & 1][0][0][0];
                    #pragma unroll
                    for (int r = 0; r < 10; ++r) xw[lane + 64 * r] = xst[r];
                }
            }
        } else {
            if (k >= 1) {
                const float* hr = &hbuf[(k - 1) & 1][0][0][0];
                #pragma unroll 1
                for (int s = 0; s < CHK; ++s) {
                    float a0A = bias0, a1A = bias1, a0B = bias0, a1B = bias1;
                    // h0(s) part, ascending j (broadcast LDS reads, float2)
                    const float2* h0A = (const float2*)(hr + s * (2 * HS));
                    const float2* h0B = (const float2*)(hr + s * (2 * HS) + HS);
                    #pragma unroll
                    for (int j2 = 0; j2 < HS / 2; ++j2) {
                        const float2 vA = h0A[j2], vB = h0B[j2];
                        a0A = fmaf(vA.x, w0[2*j2], a0A); a0A = fmaf(vA.y, w0[2*j2+1], a0A);
                        a1A = fmaf(vA.x, w1[2*j2], a1A); a1A = fmaf(vA.y, w1[2*j2+1], a1A);
                        a0B = fmaf(vB.x, w0[2*j2], a0B); a0B = fmaf(vB.y, w0[2*j2+1], a0B);
                        a1B = fmaf(vB.x, w1[2*j2], a1B); a1B = fmaf(vB.y, w1[2*j2+1], a1B);
                    }
                    // h1(s-1) part, ascending j, from SGPR broadcast
                    #pragma unroll
                    for (int j = 0; j < HS; ++j) {
                        a0A = fmaf(hsA[j], w0[HS + j], a0A);
                        a1A = fmaf(hsA[j], w1[HS + j], a1A);
                        a0B = fmaf(hsB[j], w0[HS + j], a0B);
                        a1B = fmaf(hsB[j], w1[HS + j], a1B);
                    }
                    const float act0A = (role == 1) ? tanh_fast(a0A) : sigmoid_fast(a0A);
                    const float act1A = sigmoid_fast(a1A);
                    const float act0B = (role == 1) ? tanh_fast(a0B) : sigmoid_fast(a0B);
                    const float act1B = sigmoid_fast(a1B);
                    const int sl = HS + ul;
                    const float tgA = __shfl(act0A, sl), soA = __shfl(act1A, sl);
                    const float tgB = __shfl(act0B, sl), soB = __shfl(act1B, sl);
                    cA = fmaf(act1A, cA, act0A * tgA);
                    cB = fmaf(act1B, cB, act0B * tgB);
                    const float hA = soA * tanh_fast(cA);
                    const float hB = soB * tanh_fast(cB);
                    #pragma unroll
                    for (int j = 0; j < HS; ++j) {
                        hsA[j] = rdlane(hA, j);
                        hsB[j] = rdlane(hB, j);
                    }
                }
            }
        }
        __syncthreads();   // publish h0 chunk (and staged x); 17 barriers total
    }

    // ---- final FC on h1(T-1): values are uniform in wave1's hs SGPRs ----
    if (wid == 1 && lane == 0) {
        float oA = bfc[0], oB = bfc[0];
        #pragma unroll
        for (int j = 0; j < HS; ++j) {
            const float wf = wfc[j];
            oA = fmaf(hsA[j], wf, oA);
            oB = fmaf(hsB[j], wf, oB);
        }
        out[b0] = oA;
        out[b1] = oB;
    }
}

extern "C" void kernel_launch(void* const* d_in, const int* in_sizes, int n_in,
                              void* d_out, int out_size, void* d_ws, size_t ws_size,
                              hipStream_t stream) {
    const float* x    = (const float*)d_in[0];
    const float* wih0 = (const float*)d_in[1];
    const float* whh0 = (const float*)d_in[2];
    const float* bih0 = (const float*)d_in[3];
    const float* bhh0 = (const float*)d_in[4];
    const float* wih1 = (const float*)d_in[5];
    const float* whh1 = (const float*)d_in[6];
    const float* bih1 = (const float*)d_in[7];
    const float* bhh1 = (const float*)d_in[8];
    const float* wfc  = (const float*)d_in[9];
    const float* bfc  = (const float*)d_in[10];
    float* out = (float*)d_out;

    dim3 grid(NBLK), block(128);
    hipLaunchKernelGGL(lstm2_fc_kernel, grid, block, 0, stream,
                       x, wih0, whh0, bih0, bhh0,
                       wih1, whh1, bih1, bhh1, wfc, bfc, out);
}

// Round 8
// 2732.017 us; speedup vs baseline: 2.0601x; 2.0601x over previous
//
#include <hip/hip_runtime.h>

#define T_STEPS 512
#define HS 20       // hidden size
#define F0 10       // input features (layer 0)
#define BPB 6       // batches per block: lane-group g handles batches {g, g+3}
#define NB_TOT 4096
#define NBLK ((NB_TOT + BPB - 1) / BPB)   // 683

__device__ __forceinline__ float sigmoid_fast(float v) {
    return __fdividef(1.f, 1.f + __expf(-v));
}
__device__ __forceinline__ float tanh_fast(float v) {
    return 1.f - __fdividef(2.f, __expf(2.f * v) + 1.f);
}
#define PIN(v) asm volatile("" : "+v"(v))

// Spin until *f >= tgt. Fast path: single broadcast ds_read. Backoff s_sleep.
// Trailing compiler memory fence: data reads below may not hoist above the spin.
__device__ __forceinline__ void waitflag(const volatile int* f, int tgt) {
    while (*f < tgt) __builtin_amdgcn_s_sleep(1);
    asm volatile("" ::: "memory");
}
// Publish: data writes drain (threadfence_block -> lgkmcnt(0)), then lane0 store.
__device__ __forceinline__ void pubflag(volatile int* f, int v, int lane) {
    __threadfence_block();
    if (lane == 0) *f = v;
}

// R2's verified math (735us) with BOTH per-step __syncthreads replaced by
// pairwise producer-consumer flag sync -> the L0 pair (w0 gates{i,f} -> w1
// finisher) and L1 pair (w2 -> w3) run at their own cadence instead of
// 4-wave lockstep (sum of per-phase maxima). Cross-pair coupling is only the
// h0 stream: 4-deep buffer + consumed-flags (L1 may lag <=3 steps).
// Flags (monotonic step counts, LDS):
//   flg[0] f_ex0: w0 published ex0 for steps < v
//   flg[1] f_h0 : w1 published h0  for steps < v
//   flg[2] f_ex1: w2 published ex1 | flg[3] f_h1: w3 published h1
//   flg[4] f_c2, flg[5] f_c3: w2/w3 consumed h0 for steps < v
// Hazard closure: ex0/ex1 2-deep (consumer cadence bounds writer via f_h0 /
// f_h1), h1 2-deep (w3 write at s follows f_ex1>=s+1 => w2 read of h1(s-2)
// done), h0 4-deep (w1 write at t waits f_c* >= t-3). No vmcnt drains: x
// prefetch stays in flight across flag waits. Math bit-identical to R2.
__global__ __launch_bounds__(256, 3)
void lstm2_fc_kernel(const float* __restrict__ x,
                     const float* __restrict__ wih0, const float* __restrict__ whh0,
                     const float* __restrict__ bih0, const float* __restrict__ bhh0,
                     const float* __restrict__ wih1, const float* __restrict__ whh1,
                     const float* __restrict__ bih1, const float* __restrict__ bhh1,
                     const float* __restrict__ wfc,  const float* __restrict__ bfc,
                     float* __restrict__ out)
{
    const int tid   = threadIdx.x;
    const int wid   = tid >> 6;
    const int lane  = tid & 63;
    const int g     = (lane / HS) % 3;   // lanes 60..63 shadow group 0 (benign dups)
    const int u     = lane % HS;
    const int layer = wid >> 1;          // 0: waves 0,1 | 1: waves 2,3
    const int half  = wid & 1;           // gate pair: 0 -> {i,f}, 1 -> {g,o}+finish
    const int q0    = 2 * half;
    const int bgA   = blockIdx.x * BPB + g;
    const int bgBr  = blockIdx.x * BPB + g + 3;
    const bool okB  = (bgBr < NB_TOT);
    const int bgB   = okB ? bgBr : (NB_TOT - 1);   // clamp reads

    __shared__ float s_h0[4][BPB][HS];    // h0, slot = t&3 (4-deep, cross-pair)
    __shared__ float s_h1[2][BPB][HS];    // h1, slot = s&1
    __shared__ float ex0[2][BPB][HS][2];  // {sig(i),sig(f)} L0, slot = t&1
    __shared__ float ex1[2][BPB][HS][2];  // {sig(i),sig(f)} L1, slot = s&1
    __shared__ int   flg[6];

    for (int i = tid; i < 4 * BPB * HS; i += 256) (&s_h0[0][0][0])[i] = 0.f;
    for (int i = tid; i < 2 * BPB * HS; i += 256) (&s_h1[0][0][0])[i] = 0.f;
    if (tid < 6) flg[tid] = 0;

    // ---- per-lane weights: this wave's 2 gate rows (identical to R2) ----
    float w[2][2 * HS], bias[2];
    if (layer == 0) {
        #pragma unroll
        for (int qh = 0; qh < 2; ++qh) {
            const int row = (q0 + qh) * HS + u;
            #pragma unroll
            for (int f = 0; f < F0; ++f) { w[qh][f] = wih0[row * F0 + f]; PIN(w[qh][f]); }
            #pragma unroll
            for (int j = 0; j < HS; ++j) { w[qh][F0 + j] = whh0[row * HS + j]; PIN(w[qh][F0 + j]); }
            bias[qh] = bih0[row] + bhh0[row]; PIN(bias[qh]);
        }
    } else {
        #pragma unroll
        for (int qh = 0; qh < 2; ++qh) {
            const int row = (q0 + qh) * HS + u;
            #pragma unroll
            for (int j = 0; j < HS; ++j) { w[qh][j]      = wih1[row * HS + j]; PIN(w[qh][j]); }
            #pragma unroll
            for (int j = 0; j < HS; ++j) { w[qh][HS + j] = whh1[row * HS + j]; PIN(w[qh][HS + j]); }
            bias[qh] = bih1[row] + bhh1[row]; PIN(bias[qh]);
        }
    }

    float cA = 0.f, cB = 0.f;            // carried by finisher waves only
    const float* xbA = x + (size_t)bgA * (T_STEPS * F0);
    const float* xbB = x + (size_t)bgB * (T_STEPS * F0);

    float2 xnA[F0 / 2], xnB[F0 / 2];     // L0 waves: x(t) prefetched one step ahead
    if (layer == 0) {
        const float2* pA = (const float2*)xbA;
        const float2* pB = (const float2*)xbB;
        #pragma unroll
        for (int f2 = 0; f2 < F0 / 2; ++f2) { xnA[f2] = pA[f2]; xnB[f2] = pB[f2]; }
    }

    __syncthreads();   // the ONLY block-wide barrier (init + weights published)

    if (wid == 0) {
        // ======== L0 gate wave {i,f}: produce ex0, consume h0 ========
        #pragma unroll 1
        for (int t = 0; t < T_STEPS; ++t) {
            float a0A = bias[0], a1A = bias[1], a0B = bias[0], a1B = bias[1];
            #pragma unroll
            for (int f2 = 0; f2 < F0 / 2; ++f2) {
                const int f = 2 * f2;
                const float2 vA = xnA[f2], vB = xnB[f2];
                a0A = fmaf(vA.x, w[0][f], a0A); a0A = fmaf(vA.y, w[0][f + 1], a0A);
                a1A = fmaf(vA.x, w[1][f], a1A); a1A = fmaf(vA.y, w[1][f + 1], a1A);
                a0B = fmaf(vB.x, w[0][f], a0B); a0B = fmaf(vB.y, w[0][f + 1], a0B);
                a1B = fmaf(vB.x, w[1][f], a1B); a1B = fmaf(vB.y, w[1][f + 1], a1B);
            }
            {   // issue x(t+1); stays in flight across the flag wait
                const int tn = (t + 1 < T_STEPS) ? (t + 1) : (T_STEPS - 1);
                const float2* pA = (const float2*)(xbA + tn * F0);
                const float2* pB = (const float2*)(xbB + tn * F0);
                #pragma unroll
                for (int f2 = 0; f2 < F0 / 2; ++f2) { xnA[f2] = pA[f2]; xnB[f2] = pB[f2]; }
            }
            waitflag(&flg[1], t);                  // h0(t-1) published
            const float* hpA = &s_h0[(t - 1) & 3][g][0];
            const float* hpB = &s_h0[(t - 1) & 3][g + 3][0];
            #pragma unroll
            for (int q4 = 0; q4 < HS / 4; ++q4) {
                const float4 hA = *(const float4*)(hpA + 4 * q4);
                const float4 hB = *(const float4*)(hpB + 4 * q4);
                const float eA[4] = {hA.x, hA.y, hA.z, hA.w};
                const float eB[4] = {hB.x, hB.y, hB.z, hB.w};
                #pragma unroll
                for (int e = 0; e < 4; ++e) {
                    const int k = F0 + 4 * q4 + e;
                    a0A = fmaf(eA[e], w[0][k], a0A);  a0B = fmaf(eB[e], w[0][k], a0B);
                    a1A = fmaf(eA[e], w[1][k], a1A);  a1B = fmaf(eB[e], w[1][k], a1B);
                }
            }
            *(float2*)&ex0[t & 1][g][u][0]     = make_float2(sigmoid_fast(a0A), sigmoid_fast(a1A));
            *(float2*)&ex0[t & 1][g + 3][u][0] = make_float2(sigmoid_fast(a0B), sigmoid_fast(a1B));
            pubflag(&flg[0], t + 1, lane);
        }
    } else if (wid == 1) {
        // ======== L0 finisher wave {g,o}: consume ex0, produce h0 ========
        #pragma unroll 1
        for (int t = 0; t < T_STEPS; ++t) {
            float a0A = bias[0], a1A = bias[1], a0B = bias[0], a1B = bias[1];
            #pragma unroll
            for (int f2 = 0; f2 < F0 / 2; ++f2) {
                const int f = 2 * f2;
                const float2 vA = xnA[f2], vB = xnB[f2];
                a0A = fmaf(vA.x, w[0][f], a0A); a0A = fmaf(vA.y, w[0][f + 1], a0A);
                a1A = fmaf(vA.x, w[1][f], a1A); a1A = fmaf(vA.y, w[1][f + 1], a1A);
                a0B = fmaf(vB.x, w[0][f], a0B); a0B = fmaf(vB.y, w[0][f + 1], a0B);
                a1B = fmaf(vB.x, w[1][f], a1B); a1B = fmaf(vB.y, w[1][f + 1], a1B);
            }
            {
                const int tn = (t + 1 < T_STEPS) ? (t + 1) : (T_STEPS - 1);
                const float2* pA = (const float2*)(xbA + tn * F0);
                const float2* pB = (const float2*)(xbB + tn * F0);
                #pragma unroll
                for (int f2 = 0; f2 < F0 / 2; ++f2) { xnA[f2] = pA[f2]; xnB[f2] = pB[f2]; }
            }
            // h0(t-1) is this wave's OWN previous write: no wait
            const float* hpA = &s_h0[(t - 1) & 3][g][0];
            const float* hpB = &s_h0[(t - 1) & 3][g + 3][0];
            #pragma unroll
            for (int q4 = 0; q4 < HS / 4; ++q4) {
                const float4 hA = *(const float4*)(hpA + 4 * q4);
                const float4 hB = *(const float4*)(hpB + 4 * q4);
                const float eA[4] = {hA.x, hA.y, hA.z, hA.w};
                const float eB[4] = {hB.x, hB.y, hB.z, hB.w};
                #pragma unroll
                for (int e = 0; e < 4; ++e) {
                    const int k = F0 + 4 * q4 + e;
                    a0A = fmaf(eA[e], w[0][k], a0A);  a0B = fmaf(eB[e], w[0][k], a0B);
                    a1A = fmaf(eA[e], w[1][k], a1A);  a1B = fmaf(eB[e], w[1][k], a1B);
                }
            }
            const float tgA = tanh_fast(a0A), soA = sigmoid_fast(a1A);
            const float tgB = tanh_fast(a0B), soB = sigmoid_fast(a1B);
            waitflag(&flg[0], t + 1);              // ex0(t) published
            const float2 sifA = *(const float2*)&ex0[t & 1][g][u][0];
            const float2 sifB = *(const float2*)&ex0[t & 1][g + 3][u][0];
            cA = fmaf(sifA.y, cA, sifA.x * tgA);   // c = sig(f)*c + sig(i)*tanh(g)
            cB = fmaf(sifB.y, cB, sifB.x * tgB);
            const float hA = soA * tanh_fast(cA);
            const float hB = soB * tanh_fast(cB);
            waitflag(&flg[4], t - 3);              // L1 consumed h0(t-4)
            waitflag(&flg[5], t - 3);
            s_h0[t & 3][g][u]     = hA;
            s_h0[t & 3][g + 3][u] = hB;
            pubflag(&flg[1], t + 1, lane);
        }
    } else if (wid == 2) {
        // ======== L1 gate wave {i,f}: consume h0,h1; produce ex1 ========
        #pragma unroll 1
        for (int s = 0; s < T_STEPS; ++s) {
            float a0A = bias[0], a1A = bias[1], a0B = bias[0], a1B = bias[1];
            waitflag(&flg[1], s + 1);              // h0(s) published
            const float* hpA = &s_h0[s & 3][g][0];
            const float* hpB = &s_h0[s & 3][g + 3][0];
            #pragma unroll
            for (int q4 = 0; q4 < HS / 4; ++q4) {
                const float4 hA = *(const float4*)(hpA + 4 * q4);
                const float4 hB = *(const float4*)(hpB + 4 * q4);
                const float eA[4] = {hA.x, hA.y, hA.z, hA.w};
                const float eB[4] = {hB.x, hB.y, hB.z, hB.w};
                #pragma unroll
                for (int e = 0; e < 4; ++e) {
                    const int k = 4 * q4 + e;
                    a0A = fmaf(eA[e], w[0][k], a0A);  a0B = fmaf(eB[e], w[0][k], a0B);
                    a1A = fmaf(eA[e], w[1][k], a1A);  a1B = fmaf(eB[e], w[1][k], a1B);
                }
            }
            pubflag(&flg[4], s + 1, lane);         // consumed h0(s) (reads drained)
            waitflag(&flg[3], s);                  // h1(s-1) published
            const float* ppA = &s_h1[(s - 1) & 1][g][0];
            const float* ppB = &s_h1[(s - 1) & 1][g + 3][0];
            #pragma unroll
            for (int q4 = 0; q4 < HS / 4; ++q4) {
                const float4 hA = *(const float4*)(ppA + 4 * q4);
                const float4 hB = *(const float4*)(ppB + 4 * q4);
                const float eA[4] = {hA.x, hA.y, hA.z, hA.w};
                const float eB[4] = {hB.x, hB.y, hB.z, hB.w};
                #pragma unroll
                for (int e = 0; e < 4; ++e) {
                    const int k = HS + 4 * q4 + e;
                    a0A = fmaf(eA[e], w[0][k], a0A);  a0B = fmaf(eB[e], w[0][k], a0B);
                    a1A = fmaf(eA[e], w[1][k], a1A);  a1B = fmaf(eB[e], w[1][k], a1B);
                }
            }
            *(float2*)&ex1[s & 1][g][u][0]     = make_float2(sigmoid_fast(a0A), sigmoid_fast(a1A));
            *(float2*)&ex1[s & 1][g + 3][u][0] = make_float2(sigmoid_fast(a0B), sigmoid_fast(a1B));
            pubflag(&flg[2], s + 1, lane);
        }
    } else {
        // ======== L1 finisher wave {g,o}: consume h0,ex1; produce h1 ========
        #pragma unroll 1
        for (int s = 0; s < T_STEPS; ++s) {
            float a0A = bias[0], a1A = bias[1], a0B = bias[0], a1B = bias[1];
            waitflag(&flg[1], s + 1);              // h0(s) published
            const float* hpA = &s_h0[s & 3][g][0];
            const float* hpB = &s_h0[s & 3][g + 3][0];
            #pragma unroll
            for (int q4 = 0; q4 < HS / 4; ++q4) {
                const float4 hA = *(const float4*)(hpA + 4 * q4);
                const float4 hB = *(const float4*)(hpB + 4 * q4);
                const float eA[4] = {hA.x, hA.y, hA.z, hA.w};
                const float eB[4] = {hB.x, hB.y, hB.z, hB.w};
                #pragma unroll
                for (int e = 0; e < 4; ++e) {
                    const int k = 4 * q4 + e;
                    a0A = fmaf(eA[e], w[0][k], a0A);  a0B = fmaf(eB[e], w[0][k], a0B);
                    a1A = fmaf(eA[e], w[1][k], a1A);  a1B = fmaf(eB[e], w[1][k], a1B);
                }
            }
            pubflag(&flg[5], s + 1, lane);         // consumed h0(s)
            // h1(s-1) is this wave's OWN previous write: no wait
            const float* ppA = &s_h1[(s - 1) & 1][g][0];
            const float* ppB = &s_h1[(s - 1) & 1][g + 3][0];
            #pragma unroll
            for (int q4 = 0; q4 < HS / 4; ++q4) {
                const float4 hA = *(const float4*)(ppA + 4 * q4);
                const float4 hB = *(const float4*)(ppB + 4 * q4);
                const float eA[4] = {hA.x, hA.y, hA.z, hA.w};
                const float eB[4] = {hB.x, hB.y, hB.z, hB.w};
                #pragma unroll
                for (int e = 0; e < 4; ++e) {
                    const int k = HS + 4 * q4 + e;
                    a0A = fmaf(eA[e], w[0][k], a0A);  a0B = fmaf(eB[e], w[0][k], a0B);
                    a1A = fmaf(eA[e], w[1][k], a1A);  a1B = fmaf(eB[e], w[1][k], a1B);
                }
            }
            const float tgA = tanh_fast(a0A), soA = sigmoid_fast(a1A);
            const float tgB = tanh_fast(a0B), soB = sigmoid_fast(a1B);
            waitflag(&flg[2], s + 1);              // ex1(s) published
            const float2 sifA = *(const float2*)&ex1[s & 1][g][u][0];
            const float2 sifB = *(const float2*)&ex1[s & 1][g + 3][u][0];
            cA = fmaf(sifA.y, cA, sifA.x * tgA);
            cB = fmaf(sifB.y, cB, sifB.x * tgB);
            const float hA = soA * tanh_fast(cA);
            const float hB = soB * tanh_fast(cB);
            s_h1[s & 1][g][u]     = hA;
            s_h1[s & 1][g + 3][u] = hB;
            pubflag(&flg[3], s + 1, lane);
        }
        // ---- final FC on h1(T-1), slot (T-1)&1 (own-wave writes) ----
        if (lane < 60 && u == 0) {
            const int sl = (T_STEPS - 1) & 1;
            float oA = bfc[0], oB = bfc[0];
            #pragma unroll
            for (int j = 0; j < HS; ++j) {
                oA = fmaf(s_h1[sl][g][j],     wfc[j], oA);
                oB = fmaf(s_h1[sl][g + 3][j], wfc[j], oB);
            }
            out[bgA] = oA;
            if (okB) out[bgBr] = oB;
        }
    }
}

extern "C" void kernel_launch(void* const* d_in, const int* in_sizes, int n_in,
                              void* d_out, int out_size, void* d_ws, size_t ws_size,
                              hipStream_t stream) {
    const float* x    = (const float*)d_in[0];
    const float* wih0 = (const float*)d_in[1];
    const float* whh0 = (const float*)d_in[2];
    const float* bih0 = (const float*)d_in[3];
    const float* bhh0 = (const float*)d_in[4];
    const float* wih1 = (const float*)d_in[5];
    const float* whh1 = (const float*)d_in[6];
    const float* bih1 = (const float*)d_in[7];
    const float* bhh1 = (const float*)d_in[8];
    const float* wfc  = (const float*)d_in[9];
    const float* bfc  = (const float*)d_in[10];
    float* out = (float*)d_out;

    dim3 grid(NBLK), block(256);
    hipLaunchKernelGGL(lstm2_fc_kernel, grid, block, 0, stream,
                       x, wih0, whh0, bih0, bhh0,
                       wih1, whh1, bih1, bhh1, wfc, bfc, out);
}